// Round 12
// baseline (213.414 us; speedup 1.0000x reference)
//
#include <hip/hip_runtime.h>
#include <math.h>

#define B_   2
#define N_   2048
#define D_   1024
#define H_   16
#define HD_  64
#define BH_  32
#define M_   4096   // B_*N_

typedef __bf16 bf16x8 __attribute__((ext_vector_type(8)));
typedef float  f32x4  __attribute__((ext_vector_type(4)));

__device__ inline unsigned short f2b(float f) {
    unsigned u = __float_as_uint(f);
    u += 0x7FFFu + ((u >> 16) & 1u);
    return (unsigned short)(u >> 16);
}
// cheap round (1 ulp vs RNE on ties; P has huge margin)
__device__ inline unsigned short f2b_fast(float f) {
    return (unsigned short)((__float_as_uint(f) + 0x8000u) >> 16);
}

// ---------------------------------------------------------------------------
// Convert x (4096x1024) and Wq/Wk/Wv/Wo (1024x1024 each) fp32 -> bf16 into one
// contiguous ws region: [x | wq | wk | wv | wo].  (R7-verified form; R9/R10
// showed inline conversion in GEMM K-loops costs more than this kernel.)
// ---------------------------------------------------------------------------
__global__ __launch_bounds__(256)
void cvt_all(const float* __restrict__ x,  const float* __restrict__ wq,
             const float* __restrict__ wk, const float* __restrict__ wv,
             const float* __restrict__ wo, ushort* __restrict__ dst)
{
    int i = blockIdx.x * 256 + threadIdx.x;      // float4 index
    if (i >= 2097152) return;                    // (4096*1024 + 4*1024*1024)/4
    int fi = i * 4;
    const float* s; int off;
    if (fi < 4194304) { s = x; off = fi; }
    else {
        int r = fi - 4194304;
        int wsel = r >> 20;                      // each W = 2^20 elements
        off = r & 1048575;
        s = (wsel == 0) ? wq : (wsel == 1) ? wk : (wsel == 2) ? wv : wo;
    }
    float4 f = *(const float4*)(s + off);
    ushort4 o;
    o.x = f2b(f.x); o.y = f2b(f.y); o.z = f2b(f.z); o.w = f2b(f.w);
    *(ushort4*)(dst + fi) = o;
}

// ---------------------------------------------------------------------------
// QKV bf16 MFMA GEMM (R7-verified): C = A @ W^T. 128x128 tile, 4 waves 2x2,
// 64x64/wave, BK=32. Register-prefetch staging; LDS padded [128][40].
// z=0 (Q): scaled by 0.125*log2e (exp2-domain softmax) -> [BH][N][64]
// z=1 (K): [BH][N][64];  z=2 (V): TRANSPOSED [BH][HD][N] (ushort4 stores).
// ---------------------------------------------------------------------------
__global__ __launch_bounds__(256)
void gemm_qkv(const ushort* __restrict__ A,
              const ushort* __restrict__ W0, const ushort* __restrict__ W1,
              const ushort* __restrict__ W2,
              ushort* __restrict__ O0, ushort* __restrict__ O1,
              ushort* __restrict__ O2)
{
    const int z = blockIdx.z;
    const ushort* W = (z == 0) ? W0 : (z == 1) ? W1 : W2;

    __shared__ alignas(16) ushort As[128][40];
    __shared__ alignas(16) ushort Bs[128][40];

    const int t = threadIdx.x;
    const int lane = t & 63, w = t >> 6;
    const int quad = lane >> 4, l15 = lane & 15;
    const int wm = (w >> 1) * 64, wn = (w & 1) * 64;
    const int tileM = blockIdx.x * 128, tileN = blockIdx.y * 128;

    const int r0 = t >> 2, r1 = 64 + (t >> 2);
    const int cg = (t & 3) * 8;
    const ushort* GA0 = A + (size_t)(tileM + r0) * D_ + cg;
    const ushort* GA1 = A + (size_t)(tileM + r1) * D_ + cg;
    const ushort* GB0 = W + (size_t)(tileN + r0) * D_ + cg;
    const ushort* GB1 = W + (size_t)(tileN + r1) * D_ + cg;

    f32x4 acc[4][4];
#pragma unroll
    for (int mt = 0; mt < 4; ++mt)
#pragma unroll
        for (int nt = 0; nt < 4; ++nt) acc[mt][nt] = (f32x4){0.f, 0.f, 0.f, 0.f};

    uint4 pa0 = *(const uint4*)GA0, pa1 = *(const uint4*)GA1;
    uint4 pb0 = *(const uint4*)GB0, pb1 = *(const uint4*)GB1;

    for (int k0 = 0; k0 < D_; k0 += 32) {
        __syncthreads();                 // prev tile's readers done
        *(uint4*)&As[r0][cg] = pa0;
        *(uint4*)&As[r1][cg] = pa1;
        *(uint4*)&Bs[r0][cg] = pb0;
        *(uint4*)&Bs[r1][cg] = pb1;
        __syncthreads();
        if (k0 + 32 < D_) {              // prefetch next tile (used next iter)
            pa0 = *(const uint4*)(GA0 + k0 + 32);
            pa1 = *(const uint4*)(GA1 + k0 + 32);
            pb0 = *(const uint4*)(GB0 + k0 + 32);
            pb1 = *(const uint4*)(GB1 + k0 + 32);
        }

        bf16x8 af[4], bf[4];
#pragma unroll
        for (int mt = 0; mt < 4; ++mt) af[mt] = *(const bf16x8*)&As[wm + mt * 16 + l15][quad * 8];
#pragma unroll
        for (int nt = 0; nt < 4; ++nt) bf[nt] = *(const bf16x8*)&Bs[wn + nt * 16 + l15][quad * 8];
#pragma unroll
        for (int mt = 0; mt < 4; ++mt)
#pragma unroll
            for (int nt = 0; nt < 4; ++nt)
                acc[mt][nt] = __builtin_amdgcn_mfma_f32_16x16x32_bf16(af[mt], bf[nt], acc[mt][nt], 0, 0, 0);
    }

    ushort* O = (z == 0) ? O0 : (z == 1) ? O1 : O2;
    // Q: fold 1/sqrt(64) AND log2e (exp2-domain softmax) into the scale
    const float scl = (z == 0) ? 0.18033688f : 1.0f;
#pragma unroll
    for (int mt = 0; mt < 4; ++mt)
#pragma unroll
        for (int nt = 0; nt < 4; ++nt) {
            if (z == 2) {
                // V transposed: Vt[bh][dd][n], 4 consecutive n per 8B store
                int rg0 = tileM + wm + mt * 16 + quad * 4;
                int cgc = tileN + wn + nt * 16 + l15;
                int b = rg0 >> 11, n0 = rg0 & (N_ - 1);
                int h = cgc >> 6, dd = cgc & 63;
                ushort4 o4;
                o4.x = f2b(acc[mt][nt][0]); o4.y = f2b(acc[mt][nt][1]);
                o4.z = f2b(acc[mt][nt][2]); o4.w = f2b(acc[mt][nt][3]);
                *(ushort4*)&O[((size_t)((b * H_ + h) * HD_ + dd)) * N_ + n0] = o4;
            } else {
#pragma unroll
                for (int r = 0; r < 4; ++r) {
                    int rg = tileM + wm + mt * 16 + quad * 4 + r;
                    int cgc = tileN + wn + nt * 16 + l15;
                    int b = rg >> 11, n = rg & (N_ - 1);
                    int h = cgc >> 6, dd = cgc & 63;
                    O[(((size_t)(b * H_ + h)) * N_ + n) * HD_ + dd] = f2b(acc[mt][nt][r] * scl);
                }
            }
        }
}

// ---------------------------------------------------------------------------
// Final GEMM (R7-verified bf16 form): out = AO @ Wo^T + bias, fp32 out.
// 128x64 tile (512 blocks = 2/CU). 4 waves 2x2, each 64x32.
// ---------------------------------------------------------------------------
__global__ __launch_bounds__(256)
void gemm_fin(const ushort* __restrict__ A, const ushort* __restrict__ W,
              const float* __restrict__ bias, float* __restrict__ Of)
{
    __shared__ alignas(16) ushort As[128][40];
    __shared__ alignas(16) ushort Bs[64][40];

    const int t = threadIdx.x;
    const int lane = t & 63, w = t >> 6;
    const int quad = lane >> 4, l15 = lane & 15;
    const int wm = (w >> 1) * 64, wn = (w & 1) * 32;
    const int tileM = blockIdx.x * 128, tileN = blockIdx.y * 64;

    const int r0 = t >> 2, r1 = 64 + (t >> 2);
    const int cg = (t & 3) * 8;
    const ushort* GA0 = A + (size_t)(tileM + r0) * D_ + cg;
    const ushort* GA1 = A + (size_t)(tileM + r1) * D_ + cg;
    const ushort* GB0 = W + (size_t)(tileN + r0) * D_ + cg;

    f32x4 acc[4][2];
#pragma unroll
    for (int mt = 0; mt < 4; ++mt)
#pragma unroll
        for (int nt = 0; nt < 2; ++nt) acc[mt][nt] = (f32x4){0.f, 0.f, 0.f, 0.f};

    uint4 pa0 = *(const uint4*)GA0, pa1 = *(const uint4*)GA1;
    uint4 pb0 = *(const uint4*)GB0;

    for (int k0 = 0; k0 < D_; k0 += 32) {
        __syncthreads();
        *(uint4*)&As[r0][cg] = pa0;
        *(uint4*)&As[r1][cg] = pa1;
        *(uint4*)&Bs[r0 & 63][cg] = pb0;
        __syncthreads();
        if (k0 + 32 < D_) {
            pa0 = *(const uint4*)(GA0 + k0 + 32);
            pa1 = *(const uint4*)(GA1 + k0 + 32);
            pb0 = *(const uint4*)(GB0 + k0 + 32);
        }

        bf16x8 af[4], bf[2];
#pragma unroll
        for (int mt = 0; mt < 4; ++mt) af[mt] = *(const bf16x8*)&As[wm + mt * 16 + l15][quad * 8];
#pragma unroll
        for (int nt = 0; nt < 2; ++nt) bf[nt] = *(const bf16x8*)&Bs[wn + nt * 16 + l15][quad * 8];
#pragma unroll
        for (int mt = 0; mt < 4; ++mt)
#pragma unroll
            for (int nt = 0; nt < 2; ++nt)
                acc[mt][nt] = __builtin_amdgcn_mfma_f32_16x16x32_bf16(af[mt], bf[nt], acc[mt][nt], 0, 0, 0);
    }

#pragma unroll
    for (int mt = 0; mt < 4; ++mt)
#pragma unroll
        for (int nt = 0; nt < 2; ++nt)
#pragma unroll
            for (int r = 0; r < 4; ++r) {
                int rg = tileM + wm + mt * 16 + quad * 4 + r;
                int cgc = tileN + wn + nt * 16 + l15;
                Of[(size_t)rg * D_ + cgc] = acc[mt][nt][r] + bias[cgc];
            }
}

// ---------------------------------------------------------------------------
// MFMA adaptive-temperature causal flash attention — 128-QUERY BLOCKS.
// R11 lesson: stage-count halving bought only 5% — the per-stage chain is the
// per-64-key WORK, not the barriers. So amortize each staged K/V tile over 2x
// queries: grid (16 qtt x 32 bh) = 512 blocks of 128 queries; wave w owns
// query tiles A (rows w*16..+15) and B (rows 64+w*16..+15). K-frags are read
// once from LDS and used by both tiles; total stage-executions halve.
// Ps reused sequentially per tile (same-wave DS ordering) -> LDS stays 45.3KB
// = 3 blocks/CU.
// Causal: chunks c=0..qtt (128 keys each). c<qtt: both tiles unmasked.
// c==qtt: keys 0..63 -> tile A diagonal, tile B full; keys 64..127 -> tile A
// fully masked (skipped), tile B diagonal.
// exp2 domain (Q pre-scaled 0.125*log2e): Z = sum 2^(s2-C2),
// S2 = sum (s2-C2)2^(s2-C2), H = ln2*(log2 Z - S2/Z),
// w = exp2(fma(beta, s2, -beta*C2)).  Pass 2: O += w*V, Z' += w; O/Z'.
// ---------------------------------------------------------------------------
__global__ __launch_bounds__(256)
void attn_mfma(const ushort* __restrict__ Q, const ushort* __restrict__ K,
               const ushort* __restrict__ VT, ushort* __restrict__ AO)
{
    const int bid = blockIdx.x;
    const int qtt = 15 - (bid >> 5);   // 128-query tile, LPT order
    const int bh = bid & 31;
    const size_t kvbase = (size_t)bh * N_ * HD_;

    __shared__ alignas(16) ushort Ks[128][72];      // [key][hd], 128 keys/stage
    __shared__ alignas(16) ushort Vs[64][136];      // [hd][key], 128 keys + pad
    __shared__ alignas(16) ushort Ps[4][4][296];    // wave-private P (reused A->B)

    const int t = threadIdx.x;
    const int lane = t & 63, w = t >> 6;
    const int quad = lane >> 4, l15 = lane & 15;
    const float SH2 = 11.5416913f;     // 8 * log2(e)
    const float LN2 = 0.69314718f;

    // K staging: thread covers rows skey+{0,32,64,96} of the 128-key chunk
    const int skey = t >> 3;            // 0..31
    const int skc  = (t & 7) * 8;       // 0..56
    const ushort* KS = K + kvbase + (size_t)skey * HD_ + skc;
    // V staging: thread covers hd rows vhd+{0,16,32,48}, key-cols vkc..vkc+7
    const int vhd = t >> 4;             // 0..15
    const int vkc = (t & 15) * 8;       // 0..120
    const ushort* VS = VT + kvbase + (size_t)vhd * N_ + vkc;

    const int qrowL = w * 16 + quad * 4;       // local row in a 64-query tile
    const int b = bh >> 4, h = bh & 15;
    const int nCh = qtt + 1;                   // 128-key chunks

    // Q fragments: tile A rows qtt*128 + w*16.., tile B rows +64
    bf16x8 aq0A, aq1A, aq0B, aq1B;
    {
        const size_t qrA = kvbase + (size_t)(qtt * 128 + w * 16 + l15) * HD_;
        aq0A = *(const bf16x8*)&Q[qrA + quad * 8];
        aq1A = *(const bf16x8*)&Q[qrA + 32 + quad * 8];
        aq0B = *(const bf16x8*)&Q[qrA + 64 * HD_ + quad * 8];
        aq1B = *(const bf16x8*)&Q[qrA + 64 * HD_ + 32 + quad * 8];
    }

    float ezA[4] = {0.f, 0.f, 0.f, 0.f}, szA[4] = {0.f, 0.f, 0.f, 0.f};
    float ezB[4] = {0.f, 0.f, 0.f, 0.f}, szB[4] = {0.f, 0.f, 0.f, 0.f};

    // ---------------- pass 1: Z, S2 (128-key stages, 2 query tiles) --------
    uint4 k0 = *(const uint4*)KS;
    uint4 k1 = *(const uint4*)(KS + 32 * HD_);
    uint4 k2 = *(const uint4*)(KS + 64 * HD_);
    uint4 k3 = *(const uint4*)(KS + 96 * HD_);
    for (int c = 0; c < nCh; ++c) {
        __syncthreads();
        *(uint4*)&Ks[skey][skc]      = k0;
        *(uint4*)&Ks[32 + skey][skc] = k1;
        *(uint4*)&Ks[64 + skey][skc] = k2;
        *(uint4*)&Ks[96 + skey][skc] = k3;
        __syncthreads();
        if (c + 1 < nCh) {
            const ushort* nb = KS + (size_t)(c + 1) * (128 * HD_);
            k0 = *(const uint4*)nb;
            k1 = *(const uint4*)(nb + 32 * HD_);
            k2 = *(const uint4*)(nb + 64 * HD_);
            k3 = *(const uint4*)(nb + 96 * HD_);
        }
        if (c < qtt) {                   // both tiles unmasked, 8 nt tiles
#pragma unroll
            for (int nt = 0; nt < 8; ++nt) {
                bf16x8 kf0 = *(const bf16x8*)&Ks[nt * 16 + l15][quad * 8];
                bf16x8 kf1 = *(const bf16x8*)&Ks[nt * 16 + l15][32 + quad * 8];
                f32x4 svA = (f32x4){0.f, 0.f, 0.f, 0.f};
                svA = __builtin_amdgcn_mfma_f32_16x16x32_bf16(aq0A, kf0, svA, 0, 0, 0);
                svA = __builtin_amdgcn_mfma_f32_16x16x32_bf16(aq1A, kf1, svA, 0, 0, 0);
                f32x4 svB = (f32x4){0.f, 0.f, 0.f, 0.f};
                svB = __builtin_amdgcn_mfma_f32_16x16x32_bf16(aq0B, kf0, svB, 0, 0, 0);
                svB = __builtin_amdgcn_mfma_f32_16x16x32_bf16(aq1B, kf1, svB, 0, 0, 0);
#pragma unroll
                for (int r = 0; r < 4; ++r) {
                    float shA = svA[r] - SH2, shB = svB[r] - SH2;
                    float eA = __builtin_amdgcn_exp2f(shA);
                    float eB = __builtin_amdgcn_exp2f(shB);
                    ezA[r] += eA; szA[r] = fmaf(eA, shA, szA[r]);
                    ezB[r] += eB; szB[r] = fmaf(eB, shB, szB[r]);
                }
            }
        } else {                         // c == qtt: diagonal chunk
            // nt 0..3 (keys 0..63 of chunk): tile A diag, tile B full
#pragma unroll
            for (int nt = 0; nt < 4; ++nt) {
                bf16x8 kf0 = *(const bf16x8*)&Ks[nt * 16 + l15][quad * 8];
                bf16x8 kf1 = *(const bf16x8*)&Ks[nt * 16 + l15][32 + quad * 8];
                f32x4 svA = (f32x4){0.f, 0.f, 0.f, 0.f};
                svA = __builtin_amdgcn_mfma_f32_16x16x32_bf16(aq0A, kf0, svA, 0, 0, 0);
                svA = __builtin_amdgcn_mfma_f32_16x16x32_bf16(aq1A, kf1, svA, 0, 0, 0);
                f32x4 svB = (f32x4){0.f, 0.f, 0.f, 0.f};
                svB = __builtin_amdgcn_mfma_f32_16x16x32_bf16(aq0B, kf0, svB, 0, 0, 0);
                svB = __builtin_amdgcn_mfma_f32_16x16x32_bf16(aq1B, kf1, svB, 0, 0, 0);
                const int kcol = nt * 16 + l15;
#pragma unroll
                for (int r = 0; r < 4; ++r) {
                    float shA = svA[r] - SH2, shB = svB[r] - SH2;
                    float eA = (kcol <= qrowL + r) ? __builtin_amdgcn_exp2f(shA) : 0.f;
                    float eB = __builtin_amdgcn_exp2f(shB);
                    ezA[r] += eA; szA[r] = fmaf(eA, shA, szA[r]);
                    ezB[r] += eB; szB[r] = fmaf(eB, shB, szB[r]);
                }
            }
            // nt 4..7 (keys 64..127): tile A fully masked (skip), tile B diag
#pragma unroll
            for (int nt = 4; nt < 8; ++nt) {
                bf16x8 kf0 = *(const bf16x8*)&Ks[nt * 16 + l15][quad * 8];
                bf16x8 kf1 = *(const bf16x8*)&Ks[nt * 16 + l15][32 + quad * 8];
                f32x4 svB = (f32x4){0.f, 0.f, 0.f, 0.f};
                svB = __builtin_amdgcn_mfma_f32_16x16x32_bf16(aq0B, kf0, svB, 0, 0, 0);
                svB = __builtin_amdgcn_mfma_f32_16x16x32_bf16(aq1B, kf1, svB, 0, 0, 0);
                const int kcol = (nt - 4) * 16 + l15;
#pragma unroll
                for (int r = 0; r < 4; ++r) {
                    float shB = svB[r] - SH2;
                    float eB = (kcol <= qrowL + r) ? __builtin_amdgcn_exp2f(shB) : 0.f;
                    ezB[r] += eB; szB[r] = fmaf(eB, shB, szB[r]);
                }
            }
        }
    }
    // hoisted 16-lane butterfly reduce (both tiles)
#pragma unroll
    for (int r = 0; r < 4; ++r) {
#pragma unroll
        for (int off = 1; off < 16; off <<= 1) {
            ezA[r] += __shfl_xor(ezA[r], off);
            szA[r] += __shfl_xor(szA[r], off);
            ezB[r] += __shfl_xor(ezB[r], off);
            szB[r] += __shfl_xor(szB[r], off);
        }
    }

    // ---------------- entropy -> beta (both tiles) ----------------
    float nbsA[4], blA[4], nbsB[4], blB[4];
#pragma unroll
    for (int r = 0; r < 4; ++r) {
        float Z = ezA[r];
        float Hh = LN2 * (__builtin_amdgcn_logf(Z) - szA[r] / Z);
        float bb = 1.f;
        if (Hh > 0.5f) {
            float e2 = Hh * Hh;
            float pp = -0.037f * e2 * e2 + 0.481f * e2 * Hh - 2.3f * e2 + 4.917f * Hh - 1.791f;
            bb = fmaxf(pp, 1.f);
        }
        blA[r] = bb; nbsA[r] = -bb * SH2;
        Z = ezB[r];
        Hh = LN2 * (__builtin_amdgcn_logf(Z) - szB[r] / Z);
        bb = 1.f;
        if (Hh > 0.5f) {
            float e2 = Hh * Hh;
            float pp = -0.037f * e2 * e2 + 0.481f * e2 * Hh - 2.3f * e2 + 4.917f * Hh - 1.791f;
            bb = fmaxf(pp, 1.f);
        }
        blB[r] = bb; nbsB[r] = -bb * SH2;
    }

    // ---------------- pass 2: O, Z' ----------------
    f32x4 ovA[4], ovB[4];
#pragma unroll
    for (int nt = 0; nt < 4; ++nt) {
        ovA[nt] = (f32x4){0.f, 0.f, 0.f, 0.f};
        ovB[nt] = (f32x4){0.f, 0.f, 0.f, 0.f};
    }
    float zpA[4] = {0.f, 0.f, 0.f, 0.f}, zpB[4] = {0.f, 0.f, 0.f, 0.f};

    k0 = *(const uint4*)KS;
    k1 = *(const uint4*)(KS + 32 * HD_);
    k2 = *(const uint4*)(KS + 64 * HD_);
    k3 = *(const uint4*)(KS + 96 * HD_);
    uint4 v0 = *(const uint4*)VS;
    uint4 v1 = *(const uint4*)(VS + 16 * N_);
    uint4 v2 = *(const uint4*)(VS + 32 * N_);
    uint4 v3 = *(const uint4*)(VS + 48 * N_);
    for (int c = 0; c < nCh; ++c) {
        __syncthreads();
        *(uint4*)&Ks[skey][skc]      = k0;
        *(uint4*)&Ks[32 + skey][skc] = k1;
        *(uint4*)&Ks[64 + skey][skc] = k2;
        *(uint4*)&Ks[96 + skey][skc] = k3;
        *(uint4*)&Vs[vhd][vkc]       = v0;
        *(uint4*)&Vs[16 + vhd][vkc]  = v1;
        *(uint4*)&Vs[32 + vhd][vkc]  = v2;
        *(uint4*)&Vs[48 + vhd][vkc]  = v3;
        __syncthreads();
        if (c + 1 < nCh) {
            const ushort* nk = KS + (size_t)(c + 1) * (128 * HD_);
            k0 = *(const uint4*)nk;
            k1 = *(const uint4*)(nk + 32 * HD_);
            k2 = *(const uint4*)(nk + 64 * HD_);
            k3 = *(const uint4*)(nk + 96 * HD_);
            const ushort* nv = VS + (c + 1) * 128;
            v0 = *(const uint4*)nv;
            v1 = *(const uint4*)(nv + 16 * N_);
            v2 = *(const uint4*)(nv + 32 * N_);
            v3 = *(const uint4*)(nv + 48 * N_);
        }
#pragma unroll
        for (int hh = 0; hh < 2; ++hh) {
            const bool diagA = (c == qtt && hh == 0);
            const bool skipA = (c == qtt && hh == 1);
            const bool diagB = (c == qtt && hh == 1);

            // --- tile A ---
            if (!skipA) {
                float wv[4][4];
#pragma unroll
                for (int nt = 0; nt < 4; ++nt) {
                    f32x4 sv = (f32x4){0.f, 0.f, 0.f, 0.f};
                    sv = __builtin_amdgcn_mfma_f32_16x16x32_bf16(aq0A, *(const bf16x8*)&Ks[hh * 64 + nt * 16 + l15][quad * 8], sv, 0, 0, 0);
                    sv = __builtin_amdgcn_mfma_f32_16x16x32_bf16(aq1A, *(const bf16x8*)&Ks[hh * 64 + nt * 16 + l15][32 + quad * 8], sv, 0, 0, 0);
                    const int kcol = nt * 16 + l15;
#pragma unroll
                    for (int r = 0; r < 4; ++r) {
                        float e = __builtin_amdgcn_exp2f(fmaf(blA[r], sv[r], nbsA[r]));
                        wv[nt][r] = (!diagA || (kcol <= qrowL + r)) ? e : 0.f;
                    }
                }
#pragma unroll
                for (int nt = 0; nt < 4; ++nt)
#pragma unroll
                    for (int r = 0; r < 4; ++r)
                        Ps[w][quad][r * 72 + nt * 16 + l15] = f2b_fast(wv[nt][r]);
#pragma unroll
                for (int r = 0; r < 4; ++r)
                    zpA[r] += (wv[0][r] + wv[1][r]) + (wv[2][r] + wv[3][r]);

                bf16x8 pa0 = *(const bf16x8*)&Ps[w][l15 >> 2][(l15 & 3) * 72 + quad * 8];
                bf16x8 pa1 = *(const bf16x8*)&Ps[w][l15 >> 2][(l15 & 3) * 72 + 32 + quad * 8];
#pragma unroll
                for (int nt = 0; nt < 4; ++nt) {
                    ovA[nt] = __builtin_amdgcn_mfma_f32_16x16x32_bf16(pa0, *(const bf16x8*)&Vs[nt * 16 + l15][hh * 64 + quad * 8], ovA[nt], 0, 0, 0);
                    ovA[nt] = __builtin_amdgcn_mfma_f32_16x16x32_bf16(pa1, *(const bf16x8*)&Vs[nt * 16 + l15][hh * 64 + 32 + quad * 8], ovA[nt], 0, 0, 0);
                }
            }

            // --- tile B ---
            {
                float wv[4][4];
#pragma unroll
                for (int nt = 0; nt < 4; ++nt) {
                    f32x4 sv = (f32x4){0.f, 0.f, 0.f, 0.f};
                    sv = __builtin_amdgcn_mfma_f32_16x16x32_bf16(aq0B, *(const bf16x8*)&Ks[hh * 64 + nt * 16 + l15][quad * 8], sv, 0, 0, 0);
                    sv = __builtin_amdgcn_mfma_f32_16x16x32_bf16(aq1B, *(const bf16x8*)&Ks[hh * 64 + nt * 16 + l15][32 + quad * 8], sv, 0, 0, 0);
                    const int kcol = nt * 16 + l15;
#pragma unroll
                    for (int r = 0; r < 4; ++r) {
                        float e = __builtin_amdgcn_exp2f(fmaf(blB[r], sv[r], nbsB[r]));
                        wv[nt][r] = (!diagB || (kcol <= qrowL + r)) ? e : 0.f;
                    }
                }
#pragma unroll
                for (int nt = 0; nt < 4; ++nt)
#pragma unroll
                    for (int r = 0; r < 4; ++r)
                        Ps[w][quad][r * 72 + nt * 16 + l15] = f2b_fast(wv[nt][r]);
#pragma unroll
                for (int r = 0; r < 4; ++r)
                    zpB[r] += (wv[0][r] + wv[1][r]) + (wv[2][r] + wv[3][r]);

                bf16x8 pa0 = *(const bf16x8*)&Ps[w][l15 >> 2][(l15 & 3) * 72 + quad * 8];
                bf16x8 pa1 = *(const bf16x8*)&Ps[w][l15 >> 2][(l15 & 3) * 72 + 32 + quad * 8];
#pragma unroll
                for (int nt = 0; nt < 4; ++nt) {
                    ovB[nt] = __builtin_amdgcn_mfma_f32_16x16x32_bf16(pa0, *(const bf16x8*)&Vs[nt * 16 + l15][hh * 64 + quad * 8], ovB[nt], 0, 0, 0);
                    ovB[nt] = __builtin_amdgcn_mfma_f32_16x16x32_bf16(pa1, *(const bf16x8*)&Vs[nt * 16 + l15][hh * 64 + 32 + quad * 8], ovB[nt], 0, 0, 0);
                }
            }
        }
    }
    // hoisted Z' butterfly (both tiles)
#pragma unroll
    for (int r = 0; r < 4; ++r)
#pragma unroll
        for (int off = 1; off < 16; off <<= 1) {
            zpA[r] += __shfl_xor(zpA[r], off);
            zpB[r] += __shfl_xor(zpB[r], off);
        }

    // ---------------- write AO [B, N, D] bf16 (both tiles) ----------------
#pragma unroll
    for (int r = 0; r < 4; ++r) {
        int qgA = qtt * 128 + w * 16 + quad * 4 + r;
        float invA = 1.f / zpA[r];
        float invB = 1.f / zpB[r];
        size_t roA = ((size_t)(b * N_ + qgA)) * D_ + h * HD_;
        size_t roB = ((size_t)(b * N_ + qgA + 64)) * D_ + h * HD_;
#pragma unroll
        for (int nt = 0; nt < 4; ++nt) {
            AO[roA + nt * 16 + l15] = f2b(ovA[nt][r] * invA);
            AO[roB + nt * 16 + l15] = f2b(ovB[nt][r] * invB);
        }
    }
}

// ---------------------------------------------------------------------------
extern "C" void kernel_launch(void* const* d_in, const int* in_sizes, int n_in,
                              void* d_out, int out_size, void* d_ws, size_t ws_size,
                              hipStream_t stream)
{
    const float* x  = (const float*)d_in[0];
    const float* Wq = (const float*)d_in[1];
    const float* Wk = (const float*)d_in[2];
    const float* Wv = (const float*)d_in[3];
    const float* Wo = (const float*)d_in[4];
    const float* bo = (const float*)d_in[5];
    float* out = (float*)d_out;

    ushort* ws  = (ushort*)d_ws;
    ushort* xb  = ws;                       // 4096*1024
    ushort* wqb = ws + 4194304;             // 1024*1024 each
    ushort* wkb = ws + 5242880;
    ushort* wvb = ws + 6291456;
    ushort* wob = ws + 7340032;
    ushort* Qb  = ws + 8388608;             // [32][2048][64]
    ushort* Kb  = ws + 12582912;            // [32][2048][64]
    ushort* Vtb = ws + 16777216;            // [32][64][2048]  (transposed V)
    ushort* aob = ws + 20971520;            // 4096*1024

    cvt_all<<<8192, 256, 0, stream>>>(x, Wq, Wk, Wv, Wo, xb);

    gemm_qkv<<<dim3(32, 8, 3), 256, 0, stream>>>(
        xb, wqb, wkb, wvb, Qb, Kb, Vtb);

    attn_mfma<<<dim3(512), 256, 0, stream>>>(Qb, Kb, Vtb, aob);

    gemm_fin<<<dim3(32, 16), 256, 0, stream>>>(aob, wob, bo, out);
}